// Round 2
// baseline (216.293 us; speedup 1.0000x reference)
//
#include <hip/hip_runtime.h>
#include <math.h>

#define BB 2
#define NN 4096
#define DD 8
#define HH 4
#define HID 32
#define EN 8
#define ALPHA 0.2f
#define CAP 1024

// ---------------- prep1: wh = x@W per head; wh1 = wh@a[:HID]; wh2 = wh@a[HID:]
__global__ void prep1(const float* __restrict__ x, const float* __restrict__ W,
                      const float* __restrict__ a,
                      float* __restrict__ wh, float* __restrict__ wh1,
                      float* __restrict__ wh2) {
    int gid = blockIdx.x * 256 + threadIdx.x;   // flattened (b,h,n)
    int bh = gid / NN;                          // uniform per block (NN%256==0)
    int n = gid % NN;
    int h = bh % HH;
    int b = bh / HH;
    __shared__ float sW[DD * HID];
    __shared__ float sa[2 * HID];
    if (threadIdx.x < DD * HID) sW[threadIdx.x] = W[h * DD * HID + threadIdx.x];
    if (threadIdx.x < 2 * HID)  sa[threadIdx.x] = a[h * 2 * HID + threadIdx.x];
    __syncthreads();
    float xv[DD];
#pragma unroll
    for (int k = 0; k < DD; k++) xv[k] = x[((size_t)b * NN + n) * DD + k];
    float acc1 = 0.f, acc2 = 0.f;
    float whr[HID];
#pragma unroll
    for (int d = 0; d < HID; d++) {
        float s = 0.f;
#pragma unroll
        for (int k = 0; k < DD; k++) s += xv[k] * sW[k * HID + d];
        whr[d] = s;
        acc1 += s * sa[d];
        acc2 += s * sa[HID + d];
    }
    size_t base = (size_t)bh * NN + n;
    wh1[base] = acc1;
    wh2[base] = acc2;
#pragma unroll
    for (int d = 0; d < HID; d++) wh[base * HID + d] = whr[d];
}

// ---------------- attn1: per row (b,i): compact edges, softmax over 4 heads, att@wh, ELU
__global__ void __launch_bounds__(256) attn1(
        const float* __restrict__ adj, const float* __restrict__ wh,
        const float* __restrict__ wh1, const float* __restrict__ wh2,
        float* __restrict__ hcat) {
    int row = blockIdx.x;            // b*NN + i
    int b = row / NN;
    int i = row % NN;
    int tid = threadIdx.x;
    int wave = tid >> 6, lane = tid & 63;

    __shared__ int   ej[CAP];
    __shared__ float ev[CAP];
    __shared__ float sp[HH][CAP];
    __shared__ float sL[HH];
    __shared__ int   waveCnt[4];
    __shared__ float accsh[128];

    const float* arow = adj + (size_t)row * NN;
    // each wave owns contiguous 1024 elements
    float4 vals[4];
    int cnt = 0;
#pragma unroll
    for (int q = 0; q < 4; q++) {
        int f4i = wave * 256 + q * 64 + lane;
        vals[q] = ((const float4*)arow)[f4i];
        cnt += (vals[q].x != 0.f) + (vals[q].y != 0.f) + (vals[q].z != 0.f) + (vals[q].w != 0.f);
    }
    int wcnt = cnt;
#pragma unroll
    for (int o = 1; o < 64; o <<= 1) wcnt += __shfl_xor(wcnt, o);
    if (lane == 0) waveCnt[wave] = wcnt;
    __syncthreads();
    int base = 0;
    for (int w = 0; w < wave; w++) base += waveCnt[w];
    int total = waveCnt[0] + waveCnt[1] + waveCnt[2] + waveCnt[3];
    int E = total > CAP ? CAP : total;

    int run = base;
#pragma unroll
    for (int q = 0; q < 4; q++) {
        float v4[4] = {vals[q].x, vals[q].y, vals[q].z, vals[q].w};
#pragma unroll
        for (int k = 0; k < 4; k++) {
            bool nz = (v4[k] != 0.f);
            unsigned long long m = __ballot(nz);
            int pre = __popcll(m & ((1ull << lane) - 1ull));
            if (nz) {
                int pos = run + pre;
                if (pos < CAP) {
                    ej[pos] = 4 * (wave * 256 + q * 64 + lane) + k;
                    ev[pos] = v4[k];
                }
            }
            run += __popcll(m);
        }
    }
    __syncthreads();

    // scores + softmax: wave w handles head w
    {
        int h = wave;
        float w1 = wh1[((size_t)b * HH + h) * NN + i];
        const float* w2p = wh2 + ((size_t)b * HH + h) * NN;
        float m = -INFINITY;
        for (int e = lane; e < E; e += 64) {
            float z = w1 + w2p[ej[e]];
            float lr = z > 0.f ? z : ALPHA * z;
            float s = lr * ev[e];
            sp[h][e] = s;
            m = fmaxf(m, s);
        }
#pragma unroll
        for (int o = 1; o < 64; o <<= 1) m = fmaxf(m, __shfl_xor(m, o));
        float l = 0.f;
        for (int e = lane; e < E; e += 64) {
            float p = __expf(sp[h][e] - m);
            sp[h][e] = p;
            l += p;
        }
#pragma unroll
        for (int o = 1; o < 64; o <<= 1) l += __shfl_xor(l, o);
        if (lane == 0) sL[h] = l;
    }
    __syncthreads();

    // accumulate: tid = s*128 + c ; c = h*32+d
    int c = tid & 127, s = tid >> 7;
    int h = c >> 5, d = c & 31;
    const float* whp = wh + (((size_t)b * HH + h) * NN) * HID + d;
    float acc = 0.f;
    for (int e = s; e < E; e += 2) {
        acc += sp[h][e] * whp[(size_t)ej[e] * HID];
    }
    if (s == 1) accsh[c] = acc;
    __syncthreads();
    if (s == 0) {
        acc += accsh[c];
        float l = sL[h];
        float o = (l > 0.f) ? acc / l : 0.f;
        float r = o > 0.f ? o : __expf(o) - 1.f;   // ELU
        hcat[((size_t)b * NN + i) * (HH * HID) + c] = r;
    }
}

// ---------------- prep2: whl2 = hcat@W_last; s1 = whl2@a_last[:EN]; s2 = whl2@a_last[EN:]
__global__ void prep2(const float* __restrict__ hcat, const float* __restrict__ Wl,
                      const float* __restrict__ al,
                      float* __restrict__ whl2, float* __restrict__ s1,
                      float* __restrict__ s2) {
    int gid = blockIdx.x * 256 + threadIdx.x;  // (b,n)
    __shared__ float sW[HH * HID * EN];
    __shared__ float sa[2 * EN];
    for (int k = threadIdx.x; k < HH * HID * EN; k += 256) sW[k] = Wl[k];
    if (threadIdx.x < 2 * EN) sa[threadIdx.x] = al[threadIdx.x];
    __syncthreads();
    const float* hp = hcat + (size_t)gid * (HH * HID);
    float acc[EN];
#pragma unroll
    for (int cc = 0; cc < EN; cc++) acc[cc] = 0.f;
    for (int k = 0; k < HH * HID; k++) {
        float hv = hp[k];
#pragma unroll
        for (int cc = 0; cc < EN; cc++) acc[cc] += hv * sW[k * EN + cc];
    }
    float a1 = 0.f, a2 = 0.f;
#pragma unroll
    for (int cc = 0; cc < EN; cc++) {
        a1 += acc[cc] * sa[cc];
        a2 += acc[cc] * sa[EN + cc];
        whl2[(size_t)gid * EN + cc] = acc[cc];
    }
    s1[gid] = a1;
    s2[gid] = a2;
}

// ---------------- attn2: per row: compact edges, softmax (1 head), att@whl2, ELU
__global__ void __launch_bounds__(256) attn2(
        const float* __restrict__ adj, const float* __restrict__ whl2,
        const float* __restrict__ s1, const float* __restrict__ s2,
        float* __restrict__ out) {
    int row = blockIdx.x;
    int b = row / NN;
    int tid = threadIdx.x;
    int wave = tid >> 6, lane = tid & 63;

    __shared__ int   ej[CAP];
    __shared__ float ev[CAP];
    __shared__ float sp[CAP];
    __shared__ int   waveCnt[4];
    __shared__ float sL;
    __shared__ float paccs[256];

    const float* arow = adj + (size_t)row * NN;
    float4 vals[4];
    int cnt = 0;
#pragma unroll
    for (int q = 0; q < 4; q++) {
        int f4i = wave * 256 + q * 64 + lane;
        vals[q] = ((const float4*)arow)[f4i];
        cnt += (vals[q].x != 0.f) + (vals[q].y != 0.f) + (vals[q].z != 0.f) + (vals[q].w != 0.f);
    }
    int wcnt = cnt;
#pragma unroll
    for (int o = 1; o < 64; o <<= 1) wcnt += __shfl_xor(wcnt, o);
    if (lane == 0) waveCnt[wave] = wcnt;
    __syncthreads();
    int base = 0;
    for (int w = 0; w < wave; w++) base += waveCnt[w];
    int total = waveCnt[0] + waveCnt[1] + waveCnt[2] + waveCnt[3];
    int E = total > CAP ? CAP : total;

    int run = base;
#pragma unroll
    for (int q = 0; q < 4; q++) {
        float v4[4] = {vals[q].x, vals[q].y, vals[q].z, vals[q].w};
#pragma unroll
        for (int k = 0; k < 4; k++) {
            bool nz = (v4[k] != 0.f);
            unsigned long long m = __ballot(nz);
            int pre = __popcll(m & ((1ull << lane) - 1ull));
            if (nz) {
                int pos = run + pre;
                if (pos < CAP) {
                    ej[pos] = 4 * (wave * 256 + q * 64 + lane) + k;
                    ev[pos] = v4[k];
                }
            }
            run += __popcll(m);
        }
    }
    __syncthreads();

    if (wave == 0) {
        float w1 = s1[row];
        const float* w2p = s2 + (size_t)b * NN;
        float m = -INFINITY;
        for (int e = lane; e < E; e += 64) {
            float z = w1 + w2p[ej[e]];
            float lr = z > 0.f ? z : ALPHA * z;
            float sc = lr * ev[e];
            sp[e] = sc;
            m = fmaxf(m, sc);
        }
#pragma unroll
        for (int o = 1; o < 64; o <<= 1) m = fmaxf(m, __shfl_xor(m, o));
        float l = 0.f;
        for (int e = lane; e < E; e += 64) {
            float p = __expf(sp[e] - m);
            sp[e] = p;
            l += p;
        }
#pragma unroll
        for (int o = 1; o < 64; o <<= 1) l += __shfl_xor(l, o);
        if (lane == 0) sL = l;
    }
    __syncthreads();

    int c = tid & 7, sl = tid >> 3;   // 32 slices x 8 channels
    float acc = 0.f;
    for (int e = sl; e < E; e += 32) {
        acc += sp[e] * whl2[(size_t)((size_t)b * NN + ej[e]) * EN + c];
    }
    paccs[tid] = acc;
    __syncthreads();
    if (tid < 8) {
        float t = 0.f;
        for (int s2i = 0; s2i < 32; s2i++) t += paccs[s2i * 8 + tid];
        float l = sL;
        float o = (l > 0.f) ? t / l : 0.f;
        out[(size_t)row * EN + tid] = o > 0.f ? o : __expf(o) - 1.f;
    }
}

extern "C" void kernel_launch(void* const* d_in, const int* in_sizes, int n_in,
                              void* d_out, int out_size, void* d_ws, size_t ws_size,
                              hipStream_t stream) {
    (void)in_sizes; (void)n_in; (void)out_size; (void)ws_size;
    const float* x      = (const float*)d_in[0];
    const float* adj    = (const float*)d_in[1];
    const float* W      = (const float*)d_in[2];
    const float* a      = (const float*)d_in[3];
    const float* W_last = (const float*)d_in[4];
    const float* a_last = (const float*)d_in[5];
    float* out = (float*)d_out;

    float* ws   = (float*)d_ws;
    float* wh1  = ws;                          // B*H*N
    float* wh2  = wh1 + (size_t)BB * HH * NN;  // B*H*N
    float* wh   = wh2 + (size_t)BB * HH * NN;  // B*H*N*HID
    float* hcat = wh + (size_t)BB * HH * NN * HID;   // B*N*H*HID
    float* whl2 = hcat + (size_t)BB * NN * HH * HID; // B*N*EN
    float* s1   = whl2 + (size_t)BB * NN * EN;       // B*N
    float* s2   = s1 + (size_t)BB * NN;              // B*N

    prep1<<<(BB * HH * NN) / 256, 256, 0, stream>>>(x, W, a, wh, wh1, wh2);
    attn1<<<BB * NN, 256, 0, stream>>>(adj, wh, wh1, wh2, hcat);
    prep2<<<(BB * NN) / 256, 256, 0, stream>>>(hcat, W_last, a_last, whl2, s1, s2);
    attn2<<<BB * NN, 256, 0, stream>>>(adj, whl2, s1, s2, out);
}

// Round 5
// 92.197 us; speedup vs baseline: 2.3460x; 2.3460x over previous
//
#include <hip/hip_runtime.h>
#include <math.h>

#define BB 2
#define NN 4096
#define DD 8
#define HH 4
#define HID 32
#define EN 8
#define ALPHA 0.2f
#define CAP 512   // max edges/row kept; true max deg ~270 (22 sigma margin)

// ---------------- prep1: wh(concat layout) = x@W per head; wh1/wh2 = wh@a halves
__global__ void prep1(const float* __restrict__ x, const float* __restrict__ W,
                      const float* __restrict__ a,
                      float* __restrict__ whcat, float* __restrict__ wh1,
                      float* __restrict__ wh2) {
    int gid = blockIdx.x * 256 + threadIdx.x;   // flattened (b,h,n)
    int bh = gid / NN;                          // uniform per block (NN%256==0)
    int n = gid % NN;
    int h = bh % HH;
    int b = bh / HH;
    __shared__ float sW[DD * HID];
    __shared__ float sa[2 * HID];
    if (threadIdx.x < DD * HID) sW[threadIdx.x] = W[h * DD * HID + threadIdx.x];
    if (threadIdx.x < 2 * HID)  sa[threadIdx.x] = a[h * 2 * HID + threadIdx.x];
    __syncthreads();
    float xv[DD];
#pragma unroll
    for (int k = 0; k < DD; k++) xv[k] = x[((size_t)b * NN + n) * DD + k];
    float acc1 = 0.f, acc2 = 0.f;
    float whr[HID];
#pragma unroll
    for (int d = 0; d < HID; d++) {
        float s = 0.f;
#pragma unroll
        for (int k = 0; k < DD; k++) s += xv[k] * sW[k * HID + d];
        whr[d] = s;
        acc1 += s * sa[d];
        acc2 += s * sa[HID + d];
    }
    wh1[(size_t)bh * NN + n] = acc1;
    wh2[(size_t)bh * NN + n] = acc2;
    // concat layout: whcat[b][n][h*32+d] -> contiguous 128 floats per node
    float* wp = whcat + ((size_t)b * NN + n) * (HH * HID) + h * HID;
#pragma unroll
    for (int d = 0; d < HID; d++) wp[d] = whr[d];
}

// ---------------- attn1: per row: compact edges, 4-head softmax, float4 gather, ELU
__global__ void __launch_bounds__(256) attn1(
        const float* __restrict__ adj, const float* __restrict__ whcat,
        const float* __restrict__ wh1, const float* __restrict__ wh2,
        float* __restrict__ hcat,
        int* __restrict__ ecnt, int* __restrict__ ejs, float* __restrict__ evs,
        int storeEdges) {
    int row = blockIdx.x;            // b*NN + i
    int b = row >> 12;
    int i = row & (NN - 1);
    int tid = threadIdx.x;
    int wave = tid >> 6, lane = tid & 63;

    __shared__ int   ej[CAP];
    __shared__ float ev[CAP];
    __shared__ float sp[HH][CAP];
    __shared__ float sL[HH];
    __shared__ int   waveCnt[4];
    __shared__ float4 pacc[8][32];

    const float* arow = adj + (size_t)row * NN;
    float4 vals[4];
    int cnt = 0;
#pragma unroll
    for (int q = 0; q < 4; q++) {
        int f4i = wave * 256 + q * 64 + lane;
        vals[q] = ((const float4*)arow)[f4i];
        cnt += (vals[q].x != 0.f) + (vals[q].y != 0.f) + (vals[q].z != 0.f) + (vals[q].w != 0.f);
    }
    int wcnt = cnt;
#pragma unroll
    for (int o = 1; o < 64; o <<= 1) wcnt += __shfl_xor(wcnt, o);
    if (lane == 0) waveCnt[wave] = wcnt;
    __syncthreads();
    int base = 0;
    for (int w = 0; w < wave; w++) base += waveCnt[w];
    int total = waveCnt[0] + waveCnt[1] + waveCnt[2] + waveCnt[3];
    int E = total > CAP ? CAP : total;

    int run = base;
#pragma unroll
    for (int q = 0; q < 4; q++) {
        float v4[4] = {vals[q].x, vals[q].y, vals[q].z, vals[q].w};
#pragma unroll
        for (int k = 0; k < 4; k++) {
            bool nz = (v4[k] != 0.f);
            unsigned long long m = __ballot(nz);
            int pre = __popcll(m & ((1ull << lane) - 1ull));
            if (nz) {
                int pos = run + pre;
                if (pos < CAP) {
                    ej[pos] = 4 * (wave * 256 + q * 64 + lane) + k;
                    ev[pos] = v4[k];
                }
            }
            run += __popcll(m);
        }
    }
    __syncthreads();

    // dump compacted edge list for attn2 reuse (coalesced from LDS)
    if (storeEdges) {
        if (tid == 0) ecnt[row] = E;
        for (int k = tid; k < E; k += 256) {
            ejs[(size_t)row * CAP + k] = ej[k];
            evs[(size_t)row * CAP + k] = ev[k];
        }
    }

    // scores + softmax: wave w handles head w
    {
        int h = wave;
        float w1 = wh1[((size_t)b * HH + h) * NN + i];
        const float* w2p = wh2 + ((size_t)b * HH + h) * NN;
        float m = -INFINITY;
        for (int e = lane; e < E; e += 64) {
            float z = w1 + w2p[ej[e]];
            float lr = z > 0.f ? z : ALPHA * z;
            float s = lr * ev[e];
            sp[h][e] = s;
            m = fmaxf(m, s);
        }
#pragma unroll
        for (int o = 1; o < 64; o <<= 1) m = fmaxf(m, __shfl_xor(m, o));
        float l = 0.f;
        for (int e = lane; e < E; e += 64) {
            float p = __expf(sp[h][e] - m);
            sp[h][e] = p;
            l += p;
        }
#pragma unroll
        for (int o = 1; o < 64; o <<= 1) l += __shfl_xor(l, o);
        if (lane == 0) sL[h] = l;
    }
    __syncthreads();

    // float4 gather: tid = s*32 + c4 ; 8-way E split, unroll-4, 4 indep accumulators
    {
        int s = tid >> 5, c4 = tid & 31;
        int h = c4 >> 3;
        const float4* wrow = (const float4*)whcat + (size_t)b * NN * 32 + c4;
        float4 a0 = {0,0,0,0}, a1 = a0, a2 = a0, a3 = a0;
        int e = s;
        for (; e + 24 < E; e += 32) {
            int j0 = ej[e], j1 = ej[e + 8], j2 = ej[e + 16], j3 = ej[e + 24];
            float p0 = sp[h][e], p1 = sp[h][e + 8], p2 = sp[h][e + 16], p3 = sp[h][e + 24];
            float4 v0 = wrow[(size_t)j0 * 32];
            float4 v1 = wrow[(size_t)j1 * 32];
            float4 v2 = wrow[(size_t)j2 * 32];
            float4 v3 = wrow[(size_t)j3 * 32];
            a0.x += p0 * v0.x; a0.y += p0 * v0.y; a0.z += p0 * v0.z; a0.w += p0 * v0.w;
            a1.x += p1 * v1.x; a1.y += p1 * v1.y; a1.z += p1 * v1.z; a1.w += p1 * v1.w;
            a2.x += p2 * v2.x; a2.y += p2 * v2.y; a2.z += p2 * v2.z; a2.w += p2 * v2.w;
            a3.x += p3 * v3.x; a3.y += p3 * v3.y; a3.z += p3 * v3.z; a3.w += p3 * v3.w;
        }
        for (; e < E; e += 8) {
            int j0 = ej[e];
            float p0 = sp[h][e];
            float4 v0 = wrow[(size_t)j0 * 32];
            a0.x += p0 * v0.x; a0.y += p0 * v0.y; a0.z += p0 * v0.z; a0.w += p0 * v0.w;
        }
        a0.x += a1.x + a2.x + a3.x; a0.y += a1.y + a2.y + a3.y;
        a0.z += a1.z + a2.z + a3.z; a0.w += a1.w + a2.w + a3.w;
        pacc[s][c4] = a0;
    }
    __syncthreads();
    if (tid < 32) {
        float4 t = pacc[0][tid];
#pragma unroll
        for (int s2 = 1; s2 < 8; s2++) {
            float4 u = pacc[s2][tid];
            t.x += u.x; t.y += u.y; t.z += u.z; t.w += u.w;
        }
        int h = tid >> 3;
        float l = sL[h];
        float inv = (l > 0.f) ? 1.f / l : 0.f;
        float4 r;
        float o;
        o = t.x * inv; r.x = o > 0.f ? o : __expf(o) - 1.f;
        o = t.y * inv; r.y = o > 0.f ? o : __expf(o) - 1.f;
        o = t.z * inv; r.z = o > 0.f ? o : __expf(o) - 1.f;
        o = t.w * inv; r.w = o > 0.f ? o : __expf(o) - 1.f;
        ((float4*)hcat)[(size_t)row * 32 + tid] = r;
    }
}

// ---------------- prep2: whl2 = hcat@W_last; s1/s2 = whl2@a_last halves
__global__ void prep2(const float* __restrict__ hcat, const float* __restrict__ Wl,
                      const float* __restrict__ al,
                      float* __restrict__ whl2, float* __restrict__ s1,
                      float* __restrict__ s2) {
    int gid = blockIdx.x * 256 + threadIdx.x;  // (b,n)
    __shared__ float sW[HH * HID * EN];
    __shared__ float sa[2 * EN];
    for (int k = threadIdx.x; k < HH * HID * EN; k += 256) sW[k] = Wl[k];
    if (threadIdx.x < 2 * EN) sa[threadIdx.x] = al[threadIdx.x];
    __syncthreads();
    const float* hp = hcat + (size_t)gid * (HH * HID);
    float acc[EN];
#pragma unroll
    for (int cc = 0; cc < EN; cc++) acc[cc] = 0.f;
    for (int k = 0; k < HH * HID; k++) {
        float hv = hp[k];
#pragma unroll
        for (int cc = 0; cc < EN; cc++) acc[cc] += hv * sW[k * EN + cc];
    }
    float a1 = 0.f, a2 = 0.f;
#pragma unroll
    for (int cc = 0; cc < EN; cc++) {
        a1 += acc[cc] * sa[cc];
        a2 += acc[cc] * sa[EN + cc];
        whl2[(size_t)gid * EN + cc] = acc[cc];
    }
    s1[gid] = a1;
    s2[gid] = a2;
}

// ---------------- attn2 (edge-list reuse): softmax + gather over stored lists
__global__ void __launch_bounds__(256) attn2_eg(
        const float* __restrict__ whl2, const float* __restrict__ s1,
        const float* __restrict__ s2,
        const int* __restrict__ ecnt, const int* __restrict__ ejs,
        const float* __restrict__ evs, float* __restrict__ out) {
    int row = blockIdx.x;
    int b = row >> 12;
    int tid = threadIdx.x;
    int wave = tid >> 6, lane = tid & 63;

    __shared__ int   ej2[CAP];
    __shared__ float pv[CAP];
    __shared__ float sL;
    __shared__ float pacc2[32][EN];

    int E = ecnt[row];
    for (int k = tid; k < E; k += 256) {
        ej2[k] = ejs[(size_t)row * CAP + k];
        pv[k]  = evs[(size_t)row * CAP + k];
    }
    __syncthreads();

    if (wave == 0) {
        float w1 = s1[row];
        const float* w2p = s2 + (size_t)b * NN;
        float m = -INFINITY;
        for (int e = lane; e < E; e += 64) {
            float z = w1 + w2p[ej2[e]];
            float lr = z > 0.f ? z : ALPHA * z;
            float sc = lr * pv[e];
            pv[e] = sc;
            m = fmaxf(m, sc);
        }
#pragma unroll
        for (int o = 1; o < 64; o <<= 1) m = fmaxf(m, __shfl_xor(m, o));
        float l = 0.f;
        for (int e = lane; e < E; e += 64) {
            float p = __expf(pv[e] - m);
            pv[e] = p;
            l += p;
        }
#pragma unroll
        for (int o = 1; o < 64; o <<= 1) l += __shfl_xor(l, o);
        if (lane == 0) sL = l;
    }
    __syncthreads();

    int c = tid & 7, sl = tid >> 3;   // 32-way E split x 8 channels
    const float* wp = whl2 + (size_t)b * NN * EN + c;
    float acc0 = 0.f, acc1 = 0.f;
    int e = sl;
    for (; e + 32 < E; e += 64) {
        int j0 = ej2[e], j1 = ej2[e + 32];
        float p0 = pv[e], p1 = pv[e + 32];
        acc0 += p0 * wp[(size_t)j0 * EN];
        acc1 += p1 * wp[(size_t)j1 * EN];
    }
    for (; e < E; e += 32) acc0 += pv[e] * wp[(size_t)ej2[e] * EN];
    pacc2[sl][c] = acc0 + acc1;
    __syncthreads();
    if (tid < 8) {
        float t = 0.f;
#pragma unroll
        for (int s2i = 0; s2i < 32; s2i++) t += pacc2[s2i][tid];
        float l = sL;
        float o = (l > 0.f) ? t / l : 0.f;
        out[(size_t)row * EN + tid] = o > 0.f ? o : __expf(o) - 1.f;
    }
}

// ---------------- attn2 fallback: recompact from adj (if ws too small)
__global__ void __launch_bounds__(256) attn2_adj(
        const float* __restrict__ adj, const float* __restrict__ whl2,
        const float* __restrict__ s1, const float* __restrict__ s2,
        float* __restrict__ out) {
    int row = blockIdx.x;
    int b = row >> 12;
    int tid = threadIdx.x;
    int wave = tid >> 6, lane = tid & 63;

    __shared__ int   ej[CAP];
    __shared__ float pv[CAP];
    __shared__ int   waveCnt[4];
    __shared__ float sL;
    __shared__ float pacc2[32][EN];

    const float* arow = adj + (size_t)row * NN;
    float4 vals[4];
    int cnt = 0;
#pragma unroll
    for (int q = 0; q < 4; q++) {
        int f4i = wave * 256 + q * 64 + lane;
        vals[q] = ((const float4*)arow)[f4i];
        cnt += (vals[q].x != 0.f) + (vals[q].y != 0.f) + (vals[q].z != 0.f) + (vals[q].w != 0.f);
    }
    int wcnt = cnt;
#pragma unroll
    for (int o = 1; o < 64; o <<= 1) wcnt += __shfl_xor(wcnt, o);
    if (lane == 0) waveCnt[wave] = wcnt;
    __syncthreads();
    int base = 0;
    for (int w = 0; w < wave; w++) base += waveCnt[w];
    int total = waveCnt[0] + waveCnt[1] + waveCnt[2] + waveCnt[3];
    int E = total > CAP ? CAP : total;

    int run = base;
#pragma unroll
    for (int q = 0; q < 4; q++) {
        float v4[4] = {vals[q].x, vals[q].y, vals[q].z, vals[q].w};
#pragma unroll
        for (int k = 0; k < 4; k++) {
            bool nz = (v4[k] != 0.f);
            unsigned long long m = __ballot(nz);
            int pre = __popcll(m & ((1ull << lane) - 1ull));
            if (nz) {
                int pos = run + pre;
                if (pos < CAP) {
                    ej[pos] = 4 * (wave * 256 + q * 64 + lane) + k;
                    pv[pos] = v4[k];
                }
            }
            run += __popcll(m);
        }
    }
    __syncthreads();

    if (wave == 0) {
        float w1 = s1[row];
        const float* w2p = s2 + (size_t)b * NN;
        float m = -INFINITY;
        for (int e = lane; e < E; e += 64) {
            float z = w1 + w2p[ej[e]];
            float lr = z > 0.f ? z : ALPHA * z;
            float sc = lr * pv[e];
            pv[e] = sc;
            m = fmaxf(m, sc);
        }
#pragma unroll
        for (int o = 1; o < 64; o <<= 1) m = fmaxf(m, __shfl_xor(m, o));
        float l = 0.f;
        for (int e = lane; e < E; e += 64) {
            float p = __expf(pv[e] - m);
            pv[e] = p;
            l += p;
        }
#pragma unroll
        for (int o = 1; o < 64; o <<= 1) l += __shfl_xor(l, o);
        if (lane == 0) sL = l;
    }
    __syncthreads();

    int c = tid & 7, sl = tid >> 3;
    const float* wp = whl2 + (size_t)b * NN * EN + c;
    float acc = 0.f;
    for (int e = sl; e < E; e += 32) acc += pv[e] * wp[(size_t)ej[e] * EN];
    pacc2[sl][c] = acc;
    __syncthreads();
    if (tid < 8) {
        float t = 0.f;
#pragma unroll
        for (int s2i = 0; s2i < 32; s2i++) t += pacc2[s2i][tid];
        float l = sL;
        float o = (l > 0.f) ? t / l : 0.f;
        out[(size_t)row * EN + tid] = o > 0.f ? o : __expf(o) - 1.f;
    }
}

extern "C" void kernel_launch(void* const* d_in, const int* in_sizes, int n_in,
                              void* d_out, int out_size, void* d_ws, size_t ws_size,
                              hipStream_t stream) {
    (void)in_sizes; (void)n_in; (void)out_size;
    const float* x      = (const float*)d_in[0];
    const float* adj    = (const float*)d_in[1];
    const float* W      = (const float*)d_in[2];
    const float* a      = (const float*)d_in[3];
    const float* W_last = (const float*)d_in[4];
    const float* a_last = (const float*)d_in[5];
    float* out = (float*)d_out;

    float* ws   = (float*)d_ws;
    float* wh1   = ws;                                   // B*H*N
    float* wh2   = wh1 + (size_t)BB * HH * NN;           // B*H*N
    float* whcat = wh2 + (size_t)BB * HH * NN;           // B*N*128
    float* hcat  = whcat + (size_t)BB * NN * HH * HID;   // B*N*128
    float* whl2  = hcat + (size_t)BB * NN * HH * HID;    // B*N*EN
    float* s1    = whl2 + (size_t)BB * NN * EN;          // B*N
    float* s2    = s1 + (size_t)BB * NN;                 // B*N
    float* endBase = s2 + (size_t)BB * NN;
    // edge-list store (attn1 -> attn2 reuse)
    int*   ecnt = (int*)endBase;                         // B*N
    int*   ejs  = ecnt + (size_t)BB * NN;                // B*N*CAP
    float* evs  = (float*)(ejs + (size_t)BB * NN * CAP); // B*N*CAP
    size_t needBytes = (size_t)((char*)(evs + (size_t)BB * NN * CAP) - (char*)d_ws);
    int storeEdges = (ws_size >= needBytes) ? 1 : 0;

    prep1<<<(BB * HH * NN) / 256, 256, 0, stream>>>(x, W, a, whcat, wh1, wh2);
    attn1<<<BB * NN, 256, 0, stream>>>(adj, whcat, wh1, wh2, hcat,
                                       ecnt, ejs, evs, storeEdges);
    prep2<<<(BB * NN) / 256, 256, 0, stream>>>(hcat, W_last, a_last, whl2, s1, s2);
    if (storeEdges)
        attn2_eg<<<BB * NN, 256, 0, stream>>>(whl2, s1, s2, ecnt, ejs, evs, out);
    else
        attn2_adj<<<BB * NN, 256, 0, stream>>>(adj, whl2, s1, s2, out);
}